// Round 1
// baseline (18.895 us; speedup 1.0000x reference)
//
#include <hip/hip_runtime.h>

// BKT: B=4096 students, T=512 timesteps, K=2048 skills.
// One block per student, one thread per timestep. Per-skill chains built in
// LDS via direct-mapped head table + atomicExch (unordered), then each thread
// replays its own same-skill prefix in time order (min-extraction) from k0.

#define BKT_B 4096
#define BKT_T 512
#define BKT_K 2048

__global__ __launch_bounds__(512) void bkt_kernel(
    const int* __restrict__ skills,
    const float* __restrict__ resp,
    const float* __restrict__ k0,
    const float* __restrict__ tp,
    const float* __restrict__ gp,
    const float* __restrict__ sp,
    float* __restrict__ out) {
  __shared__ int   sk_s[BKT_T];     // this student's skill ids
  __shared__ int   nxt_s[BKT_T];    // linked-list next pointers (arbitrary order)
  __shared__ float resp_s[BKT_T];   // this student's responses
  __shared__ int   head_s[BKT_K];   // direct-mapped per-skill list head

  const int b = blockIdx.x;
  const int t = threadIdx.x;
  const int base = b * BKT_T;

  // stage student row + init head table
  const int sk = skills[base + t];
  sk_s[t] = sk;
  resp_s[t] = resp[base + t];
#pragma unroll
  for (int i = 0; i < BKT_K / BKT_T; ++i)
    head_s[t + i * BKT_T] = -1;
  __syncthreads();

  // build per-skill linked lists (order irrelevant)
  nxt_s[t] = atomicExch(&head_s[sk], t);
  __syncthreads();

  // per-skill params (L1/L2 resident, 32 KB total)
  const float ss = sp[sk];
  const float gg = gp[sk];
  const float tt = tp[sk];
  float p = k0[sk];   // mastery before any touch

  // replay earlier same-skill touches in increasing time order
  int cur = -1;
  const int head = head_s[sk];
  for (;;) {
    // extract min t' with cur < t' < t in this skill's chain
    int best = 0x7fffffff;
    for (int j = head; j >= 0; j = nxt_s[j]) {
      if (j < t && j > cur) best = min(best, j);
    }
    if (best == 0x7fffffff) break;
    const float r = resp_s[best];
    float num, den;
    if (r > 0.5f) {          // correct response
      num = p * (1.0f - ss);
      den = num + (1.0f - p) * gg;
    } else {                 // incorrect response
      num = p * ss;
      den = num + (1.0f - p) * (1.0f - gg);
    }
    const float q = num / den;       // Bayesian posterior
    p = q + (1.0f - q) * tt;         // learning transition
    cur = best;
  }

  // emit mastery BEFORE the update at time t (as in reference)
  out[base + t] = p;
}

extern "C" void kernel_launch(void* const* d_in, const int* in_sizes, int n_in,
                              void* d_out, int out_size, void* d_ws, size_t ws_size,
                              hipStream_t stream) {
  const int*   skills = (const int*)d_in[0];
  const float* resp   = (const float*)d_in[1];
  const float* k0     = (const float*)d_in[2];
  const float* tp     = (const float*)d_in[3];
  const float* gp     = (const float*)d_in[4];
  const float* sp     = (const float*)d_in[5];
  float* out = (float*)d_out;

  bkt_kernel<<<BKT_B, BKT_T, 0, stream>>>(skills, resp, k0, tp, gp, sp, out);
}